// Round 1
// baseline (311.281 us; speedup 1.0000x reference)
//
#include <hip/hip_runtime.h>

#define Nn 100000
#define Ne 100000
#define NNZC 1600000
#define NBLK 256          // blocks for hist/scatter
#define CHUNK 6250        // NNZC / NBLK
#define BSH 8             // bucket = idx >> 8 (256 ids per bucket)
#define BUCKW 256
#define NBK 391           // ceil(100000/256)
#define GEMM_TOTAL 1563   // ceil(100000/64)
#define GEMM_A 782        // gemm blocks fused with hist
#define GEMM_B 781        // gemm blocks fused with scatter
#define FCAP 5888         // fine-pass LDS pair cache (23.5 KB; segments ~4096+-64)
#define SEGW 4            // segments per wave in gather (flattened streaming)

typedef __attribute__((ext_vector_type(8))) short short8;
typedef __attribute__((ext_vector_type(4))) float floatx4;

__device__ inline unsigned short f2bf(float f) {
    union { float f; unsigned int i; } c; c.f = f;
    unsigned int i = c.i;
    return (unsigned short)((i + 0x7fffu + ((i >> 16) & 1u)) >> 16);  // RNE
}
__device__ inline unsigned int f2bf2(float lo, float hi) {  // packed RNE
    union { float f; unsigned int i; } a, b;
    a.f = lo; b.f = hi;
    const unsigned int x = (a.i + 0x7fffu + ((a.i >> 16) & 1u)) >> 16;
    const unsigned int y = (b.i + 0x7fffu + ((b.i >> 16) & 1u)) & 0xffff0000u;
    return x | y;
}

// shared-memory union for the two fused kernels
union FusedLds {
    unsigned short wlds[128 * 136];           // 34816 B (gemm W staging)
    struct { int a[NBK]; int b[NBK]; } s;     // 3128 B (hist/scatter cursors)
};

// ---- gemm block body: h[64 rows] = bf16(x @ W), operand-swapped MFMA ----
// D = Wfrag(A-op) * xfrag(B-op): lane holds h[row0+r16][jb*16+q*4+r] -> direct stores.
__device__ inline void gemm_block(int gb, const float* __restrict__ x,
                                  const float* __restrict__ w,
                                  unsigned short* __restrict__ h,
                                  unsigned short* wlds, int tid) {
    const int wave = tid >> 6, lane = tid & 63;
    const int q = lane >> 4, r16 = lane & 15;

    // stage W: w[k*128+n] fp32 -> wlds[n*136+k] bf16
    for (int i = tid; i < 4096; i += 256) {
        const int k = i >> 5;
        const int n0 = (i & 31) << 2;
        const float4 wv = *(const float4*)(w + k * 128 + n0);
        wlds[(n0 + 0) * 136 + k] = f2bf(wv.x);
        wlds[(n0 + 1) * 136 + k] = f2bf(wv.y);
        wlds[(n0 + 2) * 136 + k] = f2bf(wv.z);
        wlds[(n0 + 3) * 136 + k] = f2bf(wv.w);
    }
    __syncthreads();

    const int row0 = gb * 64 + wave * 16;
    const int rrow = min(row0 + r16, Nn - 1);   // clamp: x ends on a page boundary

    floatx4 acc[8];
#pragma unroll
    for (int jb = 0; jb < 8; ++jb) acc[jb] = (floatx4){0.f, 0.f, 0.f, 0.f};

    const float* ap = x + (size_t)rrow * 128 + q * 8;
#pragma unroll
    for (int kk = 0; kk < 4; ++kk) {
        // x fragment = B-operand: B[k=q*8+j][m=r16]
        const float4 a0 = *(const float4*)(ap + kk * 32);
        const float4 a1 = *(const float4*)(ap + kk * 32 + 4);
        union { unsigned int u[4]; short8 s; } xf;
        xf.u[0] = f2bf2(a0.x, a0.y);
        xf.u[1] = f2bf2(a0.z, a0.w);
        xf.u[2] = f2bf2(a1.x, a1.y);
        xf.u[3] = f2bf2(a1.z, a1.w);
        const unsigned short* wp = wlds + kk * 32 + q * 8;
#pragma unroll
        for (int jb = 0; jb < 8; ++jb) {
            // W fragment = A-operand: A[n=r16 (within jb)][k=q*8+j]
            const short8 wf = *(const short8*)(wp + (jb * 16 + r16) * 136);
            acc[jb] = __builtin_amdgcn_mfma_f32_16x16x32_bf16(wf, xf.s, acc[jb], 0, 0, 0);
        }
    }

    // lane holds h[row0+r16][jb*16 + q*4 + r] -> 8 x 8B stores, no LDS round-trip
    if (row0 + r16 < Nn) {
        unsigned short* hb = h + (size_t)(row0 + r16) * 128 + q * 4;
#pragma unroll
        for (int jb = 0; jb < 8; ++jb) {
            uint2 o;
            o.x = f2bf2(acc[jb][0], acc[jb][1]);
            o.y = f2bf2(acc[jb][2], acc[jb][3]);
            *(uint2*)(hb + jb * 16) = o;
        }
    }
}

// ---- fused: hist (blocks [0,NBLK)) + gemm blocks [0, GEMM_A) ----
__global__ __launch_bounds__(256) void hist_gemm_kernel(
        const int* __restrict__ nidx, const int* __restrict__ eidx,
        int* __restrict__ histN, int* __restrict__ histE,
        const float* __restrict__ x, const float* __restrict__ w,
        unsigned short* __restrict__ h) {
    __shared__ FusedLds sm;
    const int tid = threadIdx.x;
    if (blockIdx.x < NBLK) {
        for (int j = tid; j < NBK; j += 256) { sm.s.a[j] = 0; sm.s.b[j] = 0; }
        __syncthreads();
        const int base = blockIdx.x * CHUNK;
        for (int i = base + tid; i < base + CHUNK; i += 256) {
            atomicAdd(&sm.s.a[nidx[i] >> BSH], 1);
            atomicAdd(&sm.s.b[eidx[i] >> BSH], 1);
        }
        __syncthreads();
        for (int j = tid; j < NBK; j += 256) {
            histN[j * NBLK + blockIdx.x] = sm.s.a[j];
            histE[j * NBLK + blockIdx.x] = sm.s.b[j];
        }
    } else {
        gemm_block(blockIdx.x - NBLK, x, w, h, sm.wlds, tid);
    }
}

// ---- scan phase 1: exclusive scan within each bucket row (256 wide) ----
__global__ void scan1_kernel(int* __restrict__ histN, int* __restrict__ histE,
                             int* __restrict__ bsumN, int* __restrict__ bsumE) {
    const int arr = blockIdx.x / NBK;
    const int b = blockIdx.x % NBK;
    int* a = arr ? histE : histN;
    int* bs = arr ? bsumE : bsumN;
    const int t = threadIdx.x;
    int v = a[b * 256 + t];
    __shared__ int tmp[2][256];
    int pin = 0;
    tmp[0][t] = v;
    for (int off = 1; off < 256; off <<= 1) {
        __syncthreads();
        int val = tmp[pin][t];
        if (t >= off) val += tmp[pin][t - off];
        tmp[1 - pin][t] = val;
        pin ^= 1;
    }
    __syncthreads();
    int incl = tmp[pin][t];
    a[b * 256 + t] = incl - v;      // exclusive within bucket row
    if (t == 255) bs[b] = incl;
}

// ---- scan phase 2: add prefix of bucket totals ----
__global__ void scan3_kernel(int* __restrict__ histN, int* __restrict__ histE,
                             const int* __restrict__ bsumN, const int* __restrict__ bsumE) {
    const int arr = blockIdx.x / NBK;
    const int b = blockIdx.x % NBK;
    int* a = arr ? histE : histN;
    const int* bs = arr ? bsumE : bsumN;
    const int t = threadIdx.x;
    int part = 0;
    for (int i = t; i < b; i += 256) part += bs[i];
    __shared__ int red[256];
    red[t] = part;
    __syncthreads();
    for (int off = 128; off > 0; off >>= 1) {
        if (t < off) red[t] += red[t + off];
        __syncthreads();
    }
    a[b * 256 + t] += red[0];
}

// ---- fused: scatter (blocks [0,NBLK)) + gemm blocks [GEMM_A, GEMM_TOTAL) ----
__global__ __launch_bounds__(256) void scatter_gemm_kernel(
        const int* __restrict__ nidx, const int* __restrict__ eidx,
        const int* __restrict__ histN, const int* __restrict__ histE,
        unsigned int* __restrict__ pairsN, unsigned int* __restrict__ pairsE,
        const float* __restrict__ x, const float* __restrict__ w,
        unsigned short* __restrict__ h) {
    __shared__ FusedLds sm;
    const int tid = threadIdx.x;
    if (blockIdx.x < NBLK) {
        const int blk = blockIdx.x;
        for (int j = tid; j < NBK; j += 256) {
            sm.s.a[j] = histN[j * NBLK + blk];
            sm.s.b[j] = histE[j * NBLK + blk];
        }
        __syncthreads();
        const int base = blk * CHUNK;
        for (int i = base + tid; i < base + CHUNK; i += 256) {
            const int n = nidx[i], e = eidx[i];
            const int pn = atomicAdd(&sm.s.a[n >> BSH], 1);
            const int pe = atomicAdd(&sm.s.b[e >> BSH], 1);
            pairsN[pn] = ((unsigned int)e << 8) | (unsigned int)(n & 255);
            pairsE[pe] = ((unsigned int)n << 8) | (unsigned int)(e & 255);
        }
    } else {
        gemm_block(GEMM_A + blockIdx.x - NBLK, x, w, h, sm.wlds, tid);
    }
}

// ---- fine pass: per-bucket local counting sort -> offs + perm (LDS pair cache) ----
__global__ void fine_kernel(const unsigned int* __restrict__ pairsN, const unsigned int* __restrict__ pairsE,
                            const int* __restrict__ histN, const int* __restrict__ histE,
                            int* __restrict__ offsN, int* __restrict__ offsE,
                            int* __restrict__ permN, int* __restrict__ permE) {
    const int arr = blockIdx.x / NBK;
    const int b = blockIdx.x % NBK;
    const unsigned int* pairs = arr ? pairsE : pairsN;
    const int* hist = arr ? histE : histN;
    int* offs = arr ? offsE : offsN;
    int* perm = arr ? permE : permN;
    const int t = threadIdx.x;  // 256
    const int S = hist[b * NBLK];
    const int E = (b + 1 < NBK) ? hist[(b + 1) * NBLK] : NNZC;
    __shared__ int cnt[BUCKW];
    __shared__ int tmp[2][BUCKW];
    __shared__ unsigned int cache[FCAP];
    cnt[t] = 0;
    __syncthreads();
    for (int i = S + t; i < E; i += BUCKW) {
        const unsigned int p = pairs[i];
        const int loc = i - S;
        if (loc < FCAP) cache[loc] = p;
        atomicAdd(&cnt[p & 255u], 1);
    }
    __syncthreads();
    int v = cnt[t];
    int pin = 0;
    tmp[0][t] = v;
    for (int off = 1; off < BUCKW; off <<= 1) {
        __syncthreads();
        int val = tmp[pin][t];
        if (t >= off) val += tmp[pin][t - off];
        tmp[1 - pin][t] = val;
        pin ^= 1;
    }
    __syncthreads();
    const int excl = tmp[pin][t] - v;
    const int id = b * BUCKW + t;
    if (id < 100000) offs[id] = S + excl;
    if (b == NBK - 1 && t == 0) offs[100000] = NNZC;
    __syncthreads();
    cnt[t] = excl;   // reuse as cursors
    __syncthreads();
    for (int i = S + t; i < E; i += BUCKW) {
        const int loc = i - S;
        const unsigned int p = (loc < FCAP) ? cache[loc] : pairs[i];
        const int pos = S + atomicAdd(&cnt[p & 255u], 1);
        perm[pos] = (int)(p >> 8);
    }
}

// ---- flattened streaming gather: each wave owns SEGW consecutive segments ----
// MODE 0: nodes->edges (h gathered, bf16 out to ef, scale 1/deg)
// MODE 1: edges->nodes (ef gathered, f32 out + bias, scale 1/deg)
// Rows [offs[e0], offs[e0+SEGW]) stream through one wave; accumulator flushes at
// (wave-uniform) segment boundaries. Removes the per-segment masked-8 tail waste
// (~25% of load slots) and the max-of-4-waves segment-length imbalance.
template <int MODE>
__global__ __launch_bounds__(256) void gather_seg_kernel(
        const int* __restrict__ perm, const int* __restrict__ offs,
        const void* __restrict__ srcv, const float* __restrict__ bias,
        void* __restrict__ outv) {
    const int wave = threadIdx.x >> 6;
    const int lane = threadIdx.x & 63;
    // readfirstlane -> e0 and everything derived (offs loads, loop bounds,
    // boundary compares) live in SGPRs: s_load + s_cmp, off the VALU.
    const int e0 = __builtin_amdgcn_readfirstlane((blockIdx.x * 4 + wave) * SEGW);
    const int start = offs[e0];
    const int end = offs[e0 + SEGW];
    const unsigned int laneoff = (unsigned int)lane << 2;
    const char* src = (const char*)srcv;

    float bx = 0.f, by = 0.f;
    if (MODE == 1) {
        const float2 b = ((const float2*)bias)[lane];
        bx = b.x; by = b.y;
    }

    float ax = 0.f, ay = 0.f;
    int e = e0;
    int seg_start = start;
    int nb = offs[e0 + 1];

    auto flush = [&](int deg) {
        const float sinv = deg ? 1.f / (float)deg : 0.f;
        if (MODE == 0) {
            *(unsigned int*)((char*)outv + (((unsigned int)e << 8) | laneoff)) =
                f2bf2(ax * sinv, ay * sinv);
        } else {
            float2 o;
            o.x = ax * sinv + bx;
            o.y = ay * sinv + by;
            *(float2*)((char*)outv + (((unsigned int)e << 9) | (laneoff << 1))) = o;
        }
        ax = 0.f; ay = 0.f;
        ++e;
    };

    int myv = 0;
    for (int i = start; i < end; i += 8) {
        const int t = (i - start) & 63;
        if (t == 0) myv = perm[min(i + lane, NNZC - 1)];
        const int m = min(end - i, 8);
        unsigned int a[8], u[8];
#pragma unroll
        for (int j = 0; j < 8; ++j)
            a[j] = ((unsigned int)__shfl(myv, t + (j < m ? j : m - 1), 64) << 8) | laneoff;
#pragma unroll
        for (int j = 0; j < 8; ++j) u[j] = *(const unsigned int*)(src + a[j]);
#pragma unroll
        for (int j = 0; j < 8; ++j) {
            if (j < m) {  // wave-uniform
                while (i + j == nb) {  // segment boundary (handles empty segments)
                    flush(nb - seg_start);
                    seg_start = nb;
                    nb = offs[e + 1];
                }
                ax += __uint_as_float(u[j] << 16);
                ay += __uint_as_float(u[j] & 0xffff0000u);
            }
        }
    }
    // remaining segments all end exactly at `end`
    while (e < e0 + SEGW) {
        flush(end - seg_start);
        seg_start = end;
    }
}

extern "C" void kernel_launch(void* const* d_in, const int* in_sizes, int n_in,
                              void* d_out, int out_size, void* d_ws, size_t ws_size,
                              hipStream_t stream) {
    const float* x = (const float*)d_in[0];
    const float* w = (const float*)d_in[1];
    const float* bias = (const float*)d_in[2];
    const int* hei = (const int*)d_in[3];
    const int* nidx = hei;            // row 0: node indices
    const int* eidx = hei + NNZC;     // row 1: edge indices
    float* out = (float*)d_out;

    // ---- carve workspace (256B-aligned chunks), ~79 MB ----
    char* p = (char*)d_ws;
    unsigned short* h = (unsigned short*)p;  p += (size_t)Nn * 128 * 2;      // 25.6 MB
    unsigned short* ef = (unsigned short*)p; p += (size_t)Ne * 128 * 2;      // 25.6 MB
    int* histN = (int*)p;                    p += (size_t)NBK * NBLK * 4 + 256;
    int* histE = (int*)p;                    p += (size_t)NBK * NBLK * 4 + 256;
    int* bsumN = (int*)p;                    p += 1792;
    int* bsumE = (int*)p;                    p += 1792;
    int* offsN = (int*)p;                    p += 400128;                    // 100001 ints
    int* offsE = (int*)p;                    p += 400128;
    int* permN = (int*)p;                    p += (size_t)NNZC * 4;          // 6.4 MB
    int* permE = (int*)p;                    p += (size_t)NNZC * 4;          // 6.4 MB
    unsigned int* pairsN = (unsigned int*)p; p += (size_t)NNZC * 4;          // 6.4 MB
    unsigned int* pairsE = (unsigned int*)p; p += (size_t)NNZC * 4;          // 6.4 MB

    // ---- CSR build with gemm halves fused into both memory-bound stages ----
    hist_gemm_kernel<<<NBLK + GEMM_A, 256, 0, stream>>>(nidx, eidx, histN, histE, x, w, h);
    scan1_kernel<<<2 * NBK, 256, 0, stream>>>(histN, histE, bsumN, bsumE);
    scan3_kernel<<<2 * NBK, 256, 0, stream>>>(histN, histE, bsumN, bsumE);
    scatter_gemm_kernel<<<NBLK + GEMM_B, 256, 0, stream>>>(nidx, eidx, histN, histE,
                                                           pairsN, pairsE, x, w, h);
    fine_kernel<<<2 * NBK, BUCKW, 0, stream>>>(pairsN, pairsE, histN, histE,
                                               offsN, offsE, permN, permE);

    // ---- two gather-side segment sums (flattened streaming form) ----
    gather_seg_kernel<0><<<Ne / (4 * SEGW), 256, 0, stream>>>(permE, offsE, h, nullptr, ef);
    gather_seg_kernel<1><<<Nn / (4 * SEGW), 256, 0, stream>>>(permN, offsN, ef, bias, out);
}